// Round 11
// baseline (190.124 us; speedup 1.0000x reference)
//
#include <hip/hip_runtime.h>
#include <hip/hip_bf16.h>

#define D 128
#define BSHIFT 5
#define BSIZE 32           // nodes per bucket
#define NBUCK 1563         // ceil(50000/32)
#define CAP 768            // staging slots per bucket (mean 512, sigma ~23; 11-sigma safe)
#define P1_EPB 8192        // pass-1 edges per block (98 blocks: halves global cursor atomics)
#define QPAD 136           // 128+8 shorts LDS row stride (2-way alias = free)
#define WPAD 264           // 256+8 shorts (gemm2 full B tile)

typedef __attribute__((ext_vector_type(8))) short bf16x8;
typedef __attribute__((ext_vector_type(4))) float floatx4;

__device__ __forceinline__ unsigned short f2bf(float f) {
    unsigned u = __float_as_uint(f);
    return (unsigned short)((u + 0x7FFFu + ((u >> 16) & 1u)) >> 16);  // RTNE
}
__device__ __forceinline__ float bf2f(unsigned short s) {
    return __uint_as_float(((unsigned)s) << 16);
}

// ---------------- Fused: blocks [0,G1B) do GEMM1; blocks [G1B, G1B+P1B) do pass1 ----------------
// pass1: per-block LDS int histogram over 1563 buckets -> one global cursor atomicAdd
// per (block,bucket). Device-scope atomic throughput ~12K/us (R4 measurement) makes the
// cursor atomics the pass1 tail -> EPB=8192 (98 blocks) halves them vs EPB=4096.
// First 16 pass1 blocks also convert Ww -> bf16 (64 KB) for gemm2's stage.
__global__ __launch_bounds__(256)
void fused_g1_p1(const float* __restrict__ h, const float* __restrict__ Qw,
                 const float* __restrict__ Qb, unsigned short* __restrict__ nsrc, int M,
                 const int* __restrict__ esrc, const int* __restrict__ edst,
                 const float* __restrict__ w, int* __restrict__ gcursor,
                 unsigned long long* __restrict__ staging,
                 const float* __restrict__ Ww, unsigned short* __restrict__ wwbf,
                 int E, int G1B) {
    __shared__ unsigned short Bs[128 * QPAD];   // 34.8 KB; pass1 aliases the front (12.5 KB)
    const int tid = threadIdx.x;

    if ((int)blockIdx.x < G1B) {
        // ---------- GEMM1 ----------
        const int lane = tid & 63;
        const int wv = tid >> 6;
        const int m0 = (blockIdx.x * 4 + wv) * 16;
        const int rquad = lane >> 4;
        const int rlow = lane & 15;
        const bool active = (m0 < M);

        bf16x8 a[4];
        if (active) {
#pragma unroll
            for (int q = 0; q < 4; ++q) {
                const float* pa = h + (size_t)(m0 + rlow) * D + q * 32 + rquad * 8;
                float4 x = *(const float4*)pa;
                float4 y = *(const float4*)(pa + 4);
                bf16x8 t;
                t[0] = (short)f2bf(x.x); t[1] = (short)f2bf(x.y);
                t[2] = (short)f2bf(x.z); t[3] = (short)f2bf(x.w);
                t[4] = (short)f2bf(y.x); t[5] = (short)f2bf(y.y);
                t[6] = (short)f2bf(y.z); t[7] = (short)f2bf(y.w);
                a[q] = t;
            }
        }

#pragma unroll
        for (int c = tid; c < 4096; c += 256) {
            int row = c >> 5, col4 = (c & 31) * 4;
            float4 x = *(const float4*)(Qw + row * 128 + col4);
            ushort4 t;
            t.x = f2bf(x.x); t.y = f2bf(x.y); t.z = f2bf(x.z); t.w = f2bf(x.w);
            *(ushort4*)&Bs[row * QPAD + col4] = t;
        }
        __syncthreads();
        if (!active) return;

        floatx4 acc[8];
#pragma unroll
        for (int n = 0; n < 8; ++n) acc[n] = (floatx4)0.f;

#pragma unroll
        for (int n = 0; n < 8; ++n) {
#pragma unroll
            for (int q = 0; q < 4; ++q) {
                bf16x8 b = *(const bf16x8*)&Bs[(n * 16 + rlow) * QPAD + q * 32 + rquad * 8];
                acc[n] = __builtin_amdgcn_mfma_f32_16x16x32_bf16(a[q], b, acc[n], 0, 0, 0);
            }
        }

#pragma unroll
        for (int n = 0; n < 8; ++n) {
            int col = n * 16 + rlow;
            float bias = Qb[col];
#pragma unroll
            for (int r = 0; r < 4; ++r) {
                int row = m0 + rquad * 4 + r;
                nsrc[(size_t)row * D + col] = f2bf(fmaxf(acc[n][r] + bias, 0.f));
            }
        }
    } else {
        const int rb = (int)blockIdx.x - G1B;
        // ---------- Ww -> bf16 conversion (first 16 pass1 blocks, 2048 elems each) ----------
        if (rb < 16) {
            for (int i = tid; i < 2048; i += 256) {
                int idx = rb * 2048 + i;          // 16*2048 = 32768 = 128*256
                wwbf[idx] = f2bf(Ww[idx]);
            }
        }
        // ---------- pass1: bucket partition (bucket = dst >> 5) ----------
        int* cnt  = (int*)Bs;           // NBUCK ints
        int* base = cnt + NBUCK;        // NBUCK ints (12.5 KB total, aliases Bs)
        const int e0 = rb * P1_EPB;
        for (int i = tid; i < NBUCK; i += 256) cnt[i] = 0;
        __syncthreads();
#pragma unroll
        for (int i = 0; i < P1_EPB; i += 256) {
            int e = e0 + i + tid;
            if (e < E) atomicAdd(&cnt[edst[e] >> BSHIFT], 1);
        }
        __syncthreads();
        for (int i = tid; i < NBUCK; i += 256) {
            int c = cnt[i];
            base[i] = (c > 0) ? atomicAdd(&gcursor[i], c) : 0;
            cnt[i] = 0;
        }
        __syncthreads();
#pragma unroll
        for (int i = 0; i < P1_EPB; i += 256) {
            int e = e0 + i + tid;
            if (e < E) {
                int d = edst[e];
                int b = d >> BSHIFT;
                int pos = base[b] + atomicAdd(&cnt[b], 1);
                if (pos < CAP) {
                    unsigned long long pk =
                        (unsigned long long)(unsigned)(esrc[e] | ((d & (BSIZE - 1)) << 16)) |
                        ((unsigned long long)__float_as_uint(w[e]) << 32);
                    staging[(size_t)b * CAP + pos] = pk;
                }
            }
        }
    }
}

// ---------------- sort_gather: one block per 32-node bucket (1563 blocks) ----------------
__global__ __launch_bounds__(256)
void sort_gather(const unsigned long long* __restrict__ staging,
                 const int* __restrict__ gcursor,
                 const unsigned short* __restrict__ nsrc,
                 unsigned short* __restrict__ nout, int N) {
    __shared__ unsigned long long csr[CAP];          // 6 KB
    __shared__ int hist[BSIZE], base_[BSIZE], cur[BSIZE];
    const int b = blockIdx.x;
    const int tid = threadIdx.x;
    const int cnt = min(gcursor[b], CAP);
    const unsigned long long* st = staging + (size_t)b * CAP;

    if (tid < BSIZE) hist[tid] = 0;
    __syncthreads();
    for (int i = tid; i < cnt; i += 256)
        atomicAdd(&hist[(int)((st[i] >> 16) & (BSIZE - 1))], 1);
    __syncthreads();

    // exclusive scan of hist[32] -> base_[32] (Hillis-Steele, double-barrier)
    int v = (tid < BSIZE) ? hist[tid] : 0;
    if (tid < BSIZE) base_[tid] = v;
    __syncthreads();
#pragma unroll
    for (int off = 1; off < BSIZE; off <<= 1) {
        int t = 0;
        if (tid < BSIZE && tid >= off) t = base_[tid - off];
        __syncthreads();
        if (tid < BSIZE) base_[tid] += t;
        __syncthreads();
    }
    if (tid < BSIZE) { base_[tid] -= v; cur[tid] = 0; }   // exclusive; zero cursors
    __syncthreads();

    // scatter into LDS CSR (sorted by node-local index)
    for (int i = tid; i < cnt; i += 256) {
        unsigned long long pk = st[i];
        int dl = (int)((pk >> 16) & (BSIZE - 1));
        int slot = base_[dl] + atomicAdd(&cur[dl], 1);
        csr[slot] = pk;
    }
    __syncthreads();

    // gather: wave wid handles nodes [wid*8, wid*8+8)
    const int wid = tid >> 6, lane = tid & 63;
    const int off2 = lane * 2;
#pragma unroll 1
    for (int k = 0; k < 8; ++k) {
        const int dl = wid * 8 + k;
        const int gnode = b * BSIZE + dl;
        if (gnode >= N) break;                 // only the last bucket is partial
        const int beg = base_[dl];
        const int num = hist[dl];

        float a0 = 0.f, a1 = 0.f, a2 = 0.f, a3 = 0.f;
        float ws0 = 0.f, ws1 = 0.f;

        int i = 0;
        for (; i + 8 <= num; i += 8) {
            unsigned long long p[8];
            unsigned vv[8];
            float wt[8];
#pragma unroll
            for (int j = 0; j < 8; ++j) p[j] = csr[beg + i + j];
#pragma unroll
            for (int j = 0; j < 8; ++j) {
                wt[j] = __uint_as_float((unsigned)(p[j] >> 32));
                vv[j] = *(const unsigned*)(nsrc + (size_t)((unsigned)p[j] & 0xFFFFu) * D + off2);
            }
#pragma unroll
            for (int j = 0; j < 8; j += 2) {
                a0 += bf2f((unsigned short)vv[j]) * wt[j];
                a1 += bf2f((unsigned short)(vv[j] >> 16)) * wt[j];
                a2 += bf2f((unsigned short)vv[j + 1]) * wt[j + 1];
                a3 += bf2f((unsigned short)(vv[j + 1] >> 16)) * wt[j + 1];
                ws0 += wt[j]; ws1 += wt[j + 1];
            }
        }
        for (; i + 4 <= num; i += 4) {
            unsigned long long p0 = csr[beg + i + 0], p1 = csr[beg + i + 1];
            unsigned long long p2 = csr[beg + i + 2], p3 = csr[beg + i + 3];
            float w0 = __uint_as_float((unsigned)(p0 >> 32));
            float w1 = __uint_as_float((unsigned)(p1 >> 32));
            float w2 = __uint_as_float((unsigned)(p2 >> 32));
            float w3 = __uint_as_float((unsigned)(p3 >> 32));
            unsigned v0 = *(const unsigned*)(nsrc + (size_t)((unsigned)p0 & 0xFFFFu) * D + off2);
            unsigned v1 = *(const unsigned*)(nsrc + (size_t)((unsigned)p1 & 0xFFFFu) * D + off2);
            unsigned v2 = *(const unsigned*)(nsrc + (size_t)((unsigned)p2 & 0xFFFFu) * D + off2);
            unsigned v3 = *(const unsigned*)(nsrc + (size_t)((unsigned)p3 & 0xFFFFu) * D + off2);
            a0 += bf2f((unsigned short)v0) * w0; a1 += bf2f((unsigned short)(v0 >> 16)) * w0;
            a2 += bf2f((unsigned short)v1) * w1; a3 += bf2f((unsigned short)(v1 >> 16)) * w1;
            a0 += bf2f((unsigned short)v2) * w2; a1 += bf2f((unsigned short)(v2 >> 16)) * w2;
            a2 += bf2f((unsigned short)v3) * w3; a3 += bf2f((unsigned short)(v3 >> 16)) * w3;
            ws0 += w0 + w2; ws1 += w1 + w3;
        }
        for (; i < num; ++i) {
            unsigned long long p = csr[beg + i];
            float wt = __uint_as_float((unsigned)(p >> 32));
            unsigned vv = *(const unsigned*)(nsrc + (size_t)((unsigned)p & 0xFFFFu) * D + off2);
            a0 += bf2f((unsigned short)vv) * wt; a1 += bf2f((unsigned short)(vv >> 16)) * wt;
            ws0 += wt;
        }

        float inv = 1.f / fmaxf(ws0 + ws1, 1.f);
        unsigned outv = (unsigned)f2bf((a0 + a2) * inv) | ((unsigned)f2bf((a1 + a3) * inv) << 16);
        *(unsigned*)(nout + (size_t)gnode * D + off2) = outv;
    }
}

// ---------------- GEMM2: out = relu([n_norm16 | cvt(h_dst)] @ wwbf^T + Wb) ----------------
// Single full-B stage (67.6 KB LDS, 2 blocks/CU with a block queue) from PRE-CONVERTED
// bf16 B: half the read bytes, zero conversion VALU in the stage loop.
__global__ __launch_bounds__(256)
void gemm2_mfma(const unsigned short* __restrict__ nnorm, const float* __restrict__ hdst,
                const unsigned short* __restrict__ wwbf, const float* __restrict__ Wb,
                float* __restrict__ out, int M) {
    __shared__ unsigned short Bs[128 * WPAD];        // 67.6 KB
    const int tid = threadIdx.x;
    const int lane = tid & 63;
    const int wv = tid >> 6;
    const int m0 = (blockIdx.x * 4 + wv) * 16;
    const int rquad = lane >> 4;
    const int rlow = lane & 15;
    const bool active = (m0 < M);

    bf16x8 a[8];
    if (active) {
#pragma unroll
        for (int q = 0; q < 4; ++q)
            a[q] = *(const bf16x8*)(nnorm + (size_t)(m0 + rlow) * D + q * 32 + rquad * 8);
#pragma unroll
        for (int q = 4; q < 8; ++q) {
            const float* pa = hdst + (size_t)(m0 + rlow) * D + (q - 4) * 32 + rquad * 8;
            float4 x = *(const float4*)pa;
            float4 y = *(const float4*)(pa + 4);
            bf16x8 t;
            t[0] = (short)f2bf(x.x); t[1] = (short)f2bf(x.y);
            t[2] = (short)f2bf(x.z); t[3] = (short)f2bf(x.w);
            t[4] = (short)f2bf(y.x); t[5] = (short)f2bf(y.y);
            t[6] = (short)f2bf(y.z); t[7] = (short)f2bf(y.w);
            a[q] = t;
        }
    }

    // stage bf16 B: 128x256 shorts as 4096 x 16B chunks, pure copies
#pragma unroll
    for (int c = tid; c < 4096; c += 256) {
        int row = c >> 5, col8 = (c & 31) * 8;
        *(bf16x8*)&Bs[row * WPAD + col8] = *(const bf16x8*)(wwbf + row * 256 + col8);
    }
    __syncthreads();
    if (!active) return;

    floatx4 acc[8];
#pragma unroll
    for (int n = 0; n < 8; ++n) acc[n] = (floatx4)0.f;

#pragma unroll
    for (int n = 0; n < 8; ++n) {
#pragma unroll
        for (int q = 0; q < 8; ++q) {
            bf16x8 b = *(const bf16x8*)&Bs[(n * 16 + rlow) * WPAD + q * 32 + rquad * 8];
            acc[n] = __builtin_amdgcn_mfma_f32_16x16x32_bf16(a[q], b, acc[n], 0, 0, 0);
        }
    }

#pragma unroll
    for (int n = 0; n < 8; ++n) {
        int col = n * 16 + rlow;
        float bias = Wb[col];
#pragma unroll
        for (int r = 0; r < 4; ++r) {
            int row = m0 + rquad * 4 + r;
            out[(size_t)row * D + col] = fmaxf(acc[n][r] + bias, 0.f);
        }
    }
}

extern "C" void kernel_launch(void* const* d_in, const int* in_sizes, int n_in,
                              void* d_out, int out_size, void* d_ws, size_t ws_size,
                              hipStream_t stream) {
    const float* h_src   = (const float*)d_in[0];
    const float* h_dst   = (const float*)d_in[1];
    const float* weights = (const float*)d_in[2];
    const int*   esrc    = (const int*)d_in[3];
    const int*   edst    = (const int*)d_in[4];
    const float* Q_w     = (const float*)d_in[5];
    const float* Q_b     = (const float*)d_in[6];
    const float* W_w     = (const float*)d_in[7];
    const float* W_b     = (const float*)d_in[8];

    const int N_SRC = in_sizes[0] / D;   // 50000
    const int N_DST = in_sizes[1] / D;   // 50000
    const int E     = in_sizes[2];       // 800000

    // workspace layout (bytes)
    char* ws = (char*)d_ws;
    int*  gcursor = (int*)ws;                                          // NBUCK ints (6.3 KB)
    unsigned long long* staging = (unsigned long long*)(ws + 8192);    // NBUCK*CAP*8 = 9.6 MB
    unsigned short* nsrc16  = (unsigned short*)(ws + 8192 + (size_t)NBUCK * CAP * 8);
    unsigned short* nnorm16 = nsrc16 + (size_t)N_SRC * D;
    unsigned short* wwbf    = nnorm16 + (size_t)N_DST * D;             // 128*256 bf16 = 64 KB

    float* out = (float*)d_out;

    const int G1B = (N_SRC + 63) / 64;                 // 782 gemm1 blocks
    const int P1B = (E + P1_EPB - 1) / P1_EPB;         // 98 pass1 blocks

    // 0) zero bucket cursors (DMA blit)
    hipMemsetAsync(gcursor, 0, NBUCK * sizeof(int), stream);

    // 1) fused: gemm1 + bucket pass1 + Ww->bf16 conversion
    fused_g1_p1<<<G1B + P1B, 256, 0, stream>>>(h_src, Q_w, Q_b, nsrc16, N_SRC,
                                               esrc, edst, weights, gcursor, staging,
                                               W_w, wwbf, E, G1B);

    // 2) per-bucket LDS sort + register-accumulate gather -> n_norm16  [1563 blocks]
    sort_gather<<<NBUCK, 256, 0, stream>>>(staging, gcursor, nsrc16, nnorm16, N_DST);

    // 3) out = relu([n_norm | h_dst] @ W^T + b)  [MFMA, bf16 B staging]
    gemm2_mfma<<<(N_DST + 63) / 64, 256, 0, stream>>>(nnorm16, h_dst, wwbf, W_b, out, N_DST);
}

// Round 13
// 184.832 us; speedup vs baseline: 1.0286x; 1.0286x over previous
//
#include <hip/hip_runtime.h>
#include <hip/hip_bf16.h>

#define D 128
#define BSHIFT 5
#define BSIZE 32           // nodes per bucket
#define NBUCK 1563         // ceil(50000/32)
#define CAP 768            // staging slots per bucket (mean 512, sigma ~23; 11-sigma safe)
#define P1_EPB 4096        // pass-1 edges per block (196 blocks — R10-proven)
#define QPAD 136           // 128+8 shorts LDS row stride (2-way alias = free)
#define WPAD 264           // 256+8 shorts (gemm2 full B tile)

typedef __attribute__((ext_vector_type(8))) short bf16x8;
typedef __attribute__((ext_vector_type(4))) float floatx4;

__device__ __forceinline__ unsigned short f2bf(float f) {
    unsigned u = __float_as_uint(f);
    return (unsigned short)((u + 0x7FFFu + ((u >> 16) & 1u)) >> 16);  // RTNE
}
__device__ __forceinline__ float bf2f(unsigned short s) {
    return __uint_as_float(((unsigned)s) << 16);
}

// ---------------- Fused: blocks [0,P1B) do pass1 (FIRST, so the latency-bound long-pole
// starts immediately and overlaps gemm1); blocks [P1B, P1B+G1B) do GEMM1. ----------------
// pass1: per-block LDS int histogram over 1563 buckets -> one global cursor atomicAdd
// per (block,bucket) -> scatter packed edges. First 16 pass1 blocks also convert
// Ww -> bf16 (64 KB) for gemm2's stage.
__global__ __launch_bounds__(256)
void fused_g1_p1(const float* __restrict__ h, const float* __restrict__ Qw,
                 const float* __restrict__ Qb, unsigned short* __restrict__ nsrc, int M,
                 const int* __restrict__ esrc, const int* __restrict__ edst,
                 const float* __restrict__ w, int* __restrict__ gcursor,
                 unsigned long long* __restrict__ staging,
                 const float* __restrict__ Ww, unsigned short* __restrict__ wwbf,
                 int E, int P1B) {
    __shared__ unsigned short Bs[128 * QPAD];   // 34.8 KB; pass1 aliases the front (12.5 KB)
    const int tid = threadIdx.x;

    if ((int)blockIdx.x >= P1B) {
        // ---------- GEMM1 ----------
        const int gb = (int)blockIdx.x - P1B;
        const int lane = tid & 63;
        const int wv = tid >> 6;
        const int m0 = (gb * 4 + wv) * 16;
        const int rquad = lane >> 4;
        const int rlow = lane & 15;
        const bool active = (m0 < M);

        bf16x8 a[4];
        if (active) {
#pragma unroll
            for (int q = 0; q < 4; ++q) {
                const float* pa = h + (size_t)(m0 + rlow) * D + q * 32 + rquad * 8;
                float4 x = *(const float4*)pa;
                float4 y = *(const float4*)(pa + 4);
                bf16x8 t;
                t[0] = (short)f2bf(x.x); t[1] = (short)f2bf(x.y);
                t[2] = (short)f2bf(x.z); t[3] = (short)f2bf(x.w);
                t[4] = (short)f2bf(y.x); t[5] = (short)f2bf(y.y);
                t[6] = (short)f2bf(y.z); t[7] = (short)f2bf(y.w);
                a[q] = t;
            }
        }

#pragma unroll
        for (int c = tid; c < 4096; c += 256) {
            int row = c >> 5, col4 = (c & 31) * 4;
            float4 x = *(const float4*)(Qw + row * 128 + col4);
            ushort4 t;
            t.x = f2bf(x.x); t.y = f2bf(x.y); t.z = f2bf(x.z); t.w = f2bf(x.w);
            *(ushort4*)&Bs[row * QPAD + col4] = t;
        }
        __syncthreads();
        if (!active) return;

        floatx4 acc[8];
#pragma unroll
        for (int n = 0; n < 8; ++n) acc[n] = (floatx4)0.f;

#pragma unroll
        for (int n = 0; n < 8; ++n) {
#pragma unroll
            for (int q = 0; q < 4; ++q) {
                bf16x8 b = *(const bf16x8*)&Bs[(n * 16 + rlow) * QPAD + q * 32 + rquad * 8];
                acc[n] = __builtin_amdgcn_mfma_f32_16x16x32_bf16(a[q], b, acc[n], 0, 0, 0);
            }
        }

#pragma unroll
        for (int n = 0; n < 8; ++n) {
            int col = n * 16 + rlow;
            float bias = Qb[col];
#pragma unroll
            for (int r = 0; r < 4; ++r) {
                int row = m0 + rquad * 4 + r;
                nsrc[(size_t)row * D + col] = f2bf(fmaxf(acc[n][r] + bias, 0.f));
            }
        }
    } else {
        const int rb = (int)blockIdx.x;
        // ---------- Ww -> bf16 conversion (first 16 pass1 blocks, 2048 elems each) ----------
        if (rb < 16) {
            for (int i = tid; i < 2048; i += 256) {
                int idx = rb * 2048 + i;          // 16*2048 = 32768 = 128*256
                wwbf[idx] = f2bf(Ww[idx]);
            }
        }
        // ---------- pass1: bucket partition (bucket = dst >> 5) ----------
        int* cnt  = (int*)Bs;           // NBUCK ints
        int* base = cnt + NBUCK;        // NBUCK ints (12.5 KB total, aliases Bs)
        const int e0 = rb * P1_EPB;
        for (int i = tid; i < NBUCK; i += 256) cnt[i] = 0;
        __syncthreads();
#pragma unroll
        for (int i = 0; i < P1_EPB; i += 256) {
            int e = e0 + i + tid;
            if (e < E) atomicAdd(&cnt[edst[e] >> BSHIFT], 1);
        }
        __syncthreads();
        for (int i = tid; i < NBUCK; i += 256) {
            int c = cnt[i];
            base[i] = (c > 0) ? atomicAdd(&gcursor[i], c) : 0;
            cnt[i] = 0;
        }
        __syncthreads();
#pragma unroll
        for (int i = 0; i < P1_EPB; i += 256) {
            int e = e0 + i + tid;
            if (e < E) {
                int d = edst[e];
                int b = d >> BSHIFT;
                int pos = base[b] + atomicAdd(&cnt[b], 1);
                if (pos < CAP) {
                    unsigned long long pk =
                        (unsigned long long)(unsigned)(esrc[e] | ((d & (BSIZE - 1)) << 16)) |
                        ((unsigned long long)__float_as_uint(w[e]) << 32);
                    staging[(size_t)b * CAP + pos] = pk;
                }
            }
        }
    }
}

// ---------------- sort_gather: one block per 32-node bucket (1563 blocks) ----------------
__global__ __launch_bounds__(256)
void sort_gather(const unsigned long long* __restrict__ staging,
                 const int* __restrict__ gcursor,
                 const unsigned short* __restrict__ nsrc,
                 unsigned short* __restrict__ nout, int N) {
    __shared__ unsigned long long csr[CAP];          // 6 KB
    __shared__ int hist[BSIZE], base_[BSIZE], cur[BSIZE];
    const int b = blockIdx.x;
    const int tid = threadIdx.x;
    const int cnt = min(gcursor[b], CAP);
    const unsigned long long* st = staging + (size_t)b * CAP;

    if (tid < BSIZE) hist[tid] = 0;
    __syncthreads();
    for (int i = tid; i < cnt; i += 256)
        atomicAdd(&hist[(int)((st[i] >> 16) & (BSIZE - 1))], 1);
    __syncthreads();

    // exclusive scan of hist[32] -> base_[32] (Hillis-Steele, double-barrier)
    int v = (tid < BSIZE) ? hist[tid] : 0;
    if (tid < BSIZE) base_[tid] = v;
    __syncthreads();
#pragma unroll
    for (int off = 1; off < BSIZE; off <<= 1) {
        int t = 0;
        if (tid < BSIZE && tid >= off) t = base_[tid - off];
        __syncthreads();
        if (tid < BSIZE) base_[tid] += t;
        __syncthreads();
    }
    if (tid < BSIZE) { base_[tid] -= v; cur[tid] = 0; }   // exclusive; zero cursors
    __syncthreads();

    // scatter into LDS CSR (sorted by node-local index)
    for (int i = tid; i < cnt; i += 256) {
        unsigned long long pk = st[i];
        int dl = (int)((pk >> 16) & (BSIZE - 1));
        int slot = base_[dl] + atomicAdd(&cur[dl], 1);
        csr[slot] = pk;
    }
    __syncthreads();

    // gather: wave wid handles nodes [wid*8, wid*8+8)
    const int wid = tid >> 6, lane = tid & 63;
    const int off2 = lane * 2;
#pragma unroll 1
    for (int k = 0; k < 8; ++k) {
        const int dl = wid * 8 + k;
        const int gnode = b * BSIZE + dl;
        if (gnode >= N) break;                 // only the last bucket is partial
        const int beg = base_[dl];
        const int num = hist[dl];

        float a0 = 0.f, a1 = 0.f, a2 = 0.f, a3 = 0.f;
        float ws0 = 0.f, ws1 = 0.f;

        int i = 0;
        for (; i + 8 <= num; i += 8) {
            unsigned long long p[8];
            unsigned vv[8];
            float wt[8];
#pragma unroll
            for (int j = 0; j < 8; ++j) p[j] = csr[beg + i + j];
#pragma unroll
            for (int j = 0; j < 8; ++j) {
                wt[j] = __uint_as_float((unsigned)(p[j] >> 32));
                vv[j] = *(const unsigned*)(nsrc + (size_t)((unsigned)p[j] & 0xFFFFu) * D + off2);
            }
#pragma unroll
            for (int j = 0; j < 8; j += 2) {
                a0 += bf2f((unsigned short)vv[j]) * wt[j];
                a1 += bf2f((unsigned short)(vv[j] >> 16)) * wt[j];
                a2 += bf2f((unsigned short)vv[j + 1]) * wt[j + 1];
                a3 += bf2f((unsigned short)(vv[j + 1] >> 16)) * wt[j + 1];
                ws0 += wt[j]; ws1 += wt[j + 1];
            }
        }
        for (; i + 4 <= num; i += 4) {
            unsigned long long p0 = csr[beg + i + 0], p1 = csr[beg + i + 1];
            unsigned long long p2 = csr[beg + i + 2], p3 = csr[beg + i + 3];
            float w0 = __uint_as_float((unsigned)(p0 >> 32));
            float w1 = __uint_as_float((unsigned)(p1 >> 32));
            float w2 = __uint_as_float((unsigned)(p2 >> 32));
            float w3 = __uint_as_float((unsigned)(p3 >> 32));
            unsigned v0 = *(const unsigned*)(nsrc + (size_t)((unsigned)p0 & 0xFFFFu) * D + off2);
            unsigned v1 = *(const unsigned*)(nsrc + (size_t)((unsigned)p1 & 0xFFFFu) * D + off2);
            unsigned v2 = *(const unsigned*)(nsrc + (size_t)((unsigned)p2 & 0xFFFFu) * D + off2);
            unsigned v3 = *(const unsigned*)(nsrc + (size_t)((unsigned)p3 & 0xFFFFu) * D + off2);
            a0 += bf2f((unsigned short)v0) * w0; a1 += bf2f((unsigned short)(v0 >> 16)) * w0;
            a2 += bf2f((unsigned short)v1) * w1; a3 += bf2f((unsigned short)(v1 >> 16)) * w1;
            a0 += bf2f((unsigned short)v2) * w2; a1 += bf2f((unsigned short)(v2 >> 16)) * w2;
            a2 += bf2f((unsigned short)v3) * w3; a3 += bf2f((unsigned short)(v3 >> 16)) * w3;
            ws0 += w0 + w2; ws1 += w1 + w3;
        }
        for (; i < num; ++i) {
            unsigned long long p = csr[beg + i];
            float wt = __uint_as_float((unsigned)(p >> 32));
            unsigned vv = *(const unsigned*)(nsrc + (size_t)((unsigned)p & 0xFFFFu) * D + off2);
            a0 += bf2f((unsigned short)vv) * wt; a1 += bf2f((unsigned short)(vv >> 16)) * wt;
            ws0 += wt;
        }

        float inv = 1.f / fmaxf(ws0 + ws1, 1.f);
        unsigned outv = (unsigned)f2bf((a0 + a2) * inv) | ((unsigned)f2bf((a1 + a3) * inv) << 16);
        *(unsigned*)(nout + (size_t)gnode * D + off2) = outv;
    }
}

// ---------------- GEMM2: out = relu([n_norm16 | cvt(h_dst)] @ wwbf^T + Wb) ----------------
// Single full-B stage (67.6 KB LDS, 2 blocks/CU with a block queue) from PRE-CONVERTED
// bf16 B: half the read bytes, zero conversion VALU in the stage loop.
__global__ __launch_bounds__(256)
void gemm2_mfma(const unsigned short* __restrict__ nnorm, const float* __restrict__ hdst,
                const unsigned short* __restrict__ wwbf, const float* __restrict__ Wb,
                float* __restrict__ out, int M) {
    __shared__ unsigned short Bs[128 * WPAD];        // 67.6 KB
    const int tid = threadIdx.x;
    const int lane = tid & 63;
    const int wv = tid >> 6;
    const int m0 = (blockIdx.x * 4 + wv) * 16;
    const int rquad = lane >> 4;
    const int rlow = lane & 15;
    const bool active = (m0 < M);

    bf16x8 a[8];
    if (active) {
#pragma unroll
        for (int q = 0; q < 4; ++q)
            a[q] = *(const bf16x8*)(nnorm + (size_t)(m0 + rlow) * D + q * 32 + rquad * 8);
#pragma unroll
        for (int q = 4; q < 8; ++q) {
            const float* pa = hdst + (size_t)(m0 + rlow) * D + (q - 4) * 32 + rquad * 8;
            float4 x = *(const float4*)pa;
            float4 y = *(const float4*)(pa + 4);
            bf16x8 t;
            t[0] = (short)f2bf(x.x); t[1] = (short)f2bf(x.y);
            t[2] = (short)f2bf(x.z); t[3] = (short)f2bf(x.w);
            t[4] = (short)f2bf(y.x); t[5] = (short)f2bf(y.y);
            t[6] = (short)f2bf(y.z); t[7] = (short)f2bf(y.w);
            a[q] = t;
        }
    }

    // stage bf16 B: 128x256 shorts as 4096 x 16B chunks, pure copies
#pragma unroll
    for (int c = tid; c < 4096; c += 256) {
        int row = c >> 5, col8 = (c & 31) * 8;
        *(bf16x8*)&Bs[row * WPAD + col8] = *(const bf16x8*)(wwbf + row * 256 + col8);
    }
    __syncthreads();
    if (!active) return;

    floatx4 acc[8];
#pragma unroll
    for (int n = 0; n < 8; ++n) acc[n] = (floatx4)0.f;

#pragma unroll
    for (int n = 0; n < 8; ++n) {
#pragma unroll
        for (int q = 0; q < 8; ++q) {
            bf16x8 b = *(const bf16x8*)&Bs[(n * 16 + rlow) * WPAD + q * 32 + rquad * 8];
            acc[n] = __builtin_amdgcn_mfma_f32_16x16x32_bf16(a[q], b, acc[n], 0, 0, 0);
        }
    }

#pragma unroll
    for (int n = 0; n < 8; ++n) {
        int col = n * 16 + rlow;
        float bias = Wb[col];
#pragma unroll
        for (int r = 0; r < 4; ++r) {
            int row = m0 + rquad * 4 + r;
            out[(size_t)row * D + col] = fmaxf(acc[n][r] + bias, 0.f);
        }
    }
}

extern "C" void kernel_launch(void* const* d_in, const int* in_sizes, int n_in,
                              void* d_out, int out_size, void* d_ws, size_t ws_size,
                              hipStream_t stream) {
    const float* h_src   = (const float*)d_in[0];
    const float* h_dst   = (const float*)d_in[1];
    const float* weights = (const float*)d_in[2];
    const int*   esrc    = (const int*)d_in[3];
    const int*   edst    = (const int*)d_in[4];
    const float* Q_w     = (const float*)d_in[5];
    const float* Q_b     = (const float*)d_in[6];
    const float* W_w     = (const float*)d_in[7];
    const float* W_b     = (const float*)d_in[8];

    const int N_SRC = in_sizes[0] / D;   // 50000
    const int N_DST = in_sizes[1] / D;   // 50000
    const int E     = in_sizes[2];       // 800000

    // workspace layout (bytes)
    char* ws = (char*)d_ws;
    int*  gcursor = (int*)ws;                                          // NBUCK ints (6.3 KB)
    unsigned long long* staging = (unsigned long long*)(ws + 8192);    // NBUCK*CAP*8 = 9.6 MB
    unsigned short* nsrc16  = (unsigned short*)(ws + 8192 + (size_t)NBUCK * CAP * 8);
    unsigned short* nnorm16 = nsrc16 + (size_t)N_SRC * D;
    unsigned short* wwbf    = nnorm16 + (size_t)N_DST * D;             // 128*256 bf16 = 64 KB

    float* out = (float*)d_out;

    const int G1B = (N_SRC + 63) / 64;                 // 782 gemm1 blocks
    const int P1B = (E + P1_EPB - 1) / P1_EPB;         // 196 pass1 blocks

    // 0) zero bucket cursors (DMA blit)
    hipMemsetAsync(gcursor, 0, NBUCK * sizeof(int), stream);

    // 1) fused: pass1 FIRST (blocks [0,P1B)) + gemm1 (blocks [P1B, P1B+G1B))
    fused_g1_p1<<<P1B + G1B, 256, 0, stream>>>(h_src, Q_w, Q_b, nsrc16, N_SRC,
                                               esrc, edst, weights, gcursor, staging,
                                               W_w, wwbf, E, P1B);

    // 2) per-bucket LDS sort + register-accumulate gather -> n_norm16  [1563 blocks]
    sort_gather<<<NBUCK, 256, 0, stream>>>(staging, gcursor, nsrc16, nnorm16, N_DST);

    // 3) out = relu([n_norm | h_dst] @ W^T + b)  [MFMA, bf16 B staging]
    gemm2_mfma<<<(N_DST + 63) / 64, 256, 0, stream>>>(nnorm16, h_dst, wwbf, W_b, out, N_DST);
}